// Round 8
// baseline (2084.928 us; speedup 1.0000x reference)
//
#include <hip/hip_runtime.h>
#include <hip/hip_bf16.h>

#define B_GRAPHS 64
#define NPER     2048
#define T_NODES  (B_GRAPHS*NPER)
#define D_DIM    256
#define U_DIM    128
#define TU       384   // 3*U
#define XPW      768   // 2*TU (fwd|bwd)

typedef unsigned short ushortT;
typedef unsigned int   uint32;

typedef __attribute__((ext_vector_type(4))) float  f32x4;
typedef __attribute__((ext_vector_type(8))) __bf16 bf16x8;
typedef _Float16 f16;
typedef __attribute__((ext_vector_type(8))) _Float16 f16x8;

#define GAS __attribute__((address_space(1)))
#define LOG2E_F 1.4426950408889634f

static __device__ __forceinline__ ushortT f2bf(float f) {
  union { float f; uint32 u; } a; a.f = f;
  uint32 u = a.u;
  return (ushortT)((u + 0x7fffu + ((u >> 16) & 1u)) >> 16);   // RTNE
}
static __device__ __forceinline__ float bf2f(ushortT h) {
  union { uint32 u; float f; } a; a.u = ((uint32)h) << 16; return a.f;
}
static __device__ __forceinline__ float rcpf(float x) {
#if __has_builtin(__builtin_amdgcn_rcpf)
  return __builtin_amdgcn_rcpf(x);
#else
  return 1.0f / x;
#endif
}
static __device__ __forceinline__ float exp2f_hw(float x) {
#if __has_builtin(__builtin_amdgcn_exp2f)
  return __builtin_amdgcn_exp2f(x);
#else
  return __expf(0.69314718055994531f * x);
#endif
}
static __device__ __forceinline__ ushortT gload_u16(const ushortT* p) {
  return *(const GAS ushortT*)p;
}
static __device__ __forceinline__ void gstore_u16(ushortT* p, ushortT v) {
  *(GAS ushortT*)p = v;
}

// ---------------- prep: Wt[2][768][256] bf16 (transposed concat of K_fwd|K_bwd), b0[2][768] f32
// NOTE: z,r columns prescaled by log2e; h columns by 2*log2e (lets rec use exp2 directly).
__global__ __launch_bounds__(256) void prep_kernel(
    const float* __restrict__ Kf, const float* __restrict__ Kb,
    const float* __restrict__ bfw, const float* __restrict__ bbw,
    ushortT* __restrict__ Wt, float* __restrict__ b0)
{
  int idx = blockIdx.x * 256 + threadIdx.x;
  if (idx < 2 * XPW * D_DIM) {
    int l = idx / (XPW * D_DIM);
    int rem = idx % (XPW * D_DIM);
    int c = rem / D_DIM, k = rem % D_DIM;
    float v = (c < TU) ? Kf[(size_t)l * D_DIM * TU + (size_t)k * TU + c]
                       : Kb[(size_t)l * D_DIM * TU + (size_t)k * TU + (c - TU)];
    float sc = ((c % TU) < 256) ? LOG2E_F : 2.0f * LOG2E_F;
    Wt[idx] = f2bf(v * sc);
  } else {
    int i2 = idx - 2 * XPW * D_DIM;
    if (i2 < 2 * XPW) {
      int l = i2 / XPW, c = i2 % XPW;
      float v = (c < TU) ? bfw[l * 2 * TU + c] : bbw[l * 2 * TU + (c - TU)];
      float sc = ((c % TU) < 256) ? LOG2E_F : 2.0f * LOG2E_F;
      b0[i2] = v * sc;
    }
  }
}

// ---------------- nodeof[g][slot] = node index ; L[g] = leaf count (positions are a perm of 1..L)
__global__ __launch_bounds__(256) void nodeofL_kernel(
    const int* __restrict__ pos, int* __restrict__ nodeof, int* __restrict__ L)
{
  int g = blockIdx.x, tid = threadIdx.x;
  __shared__ int red[256];
  int cnt = 0;
  for (int i = 0; i < NPER / 256; ++i) {
    int t = g * NPER + i * 256 + tid;
    int p = pos[t];
    if (p) { nodeof[g * NPER + p - 1] = t; cnt++; }
  }
  red[tid] = cnt; __syncthreads();
  for (int s = 128; s > 0; s >>= 1) {
    if (tid < s) red[tid] += red[tid + s];
    __syncthreads();
  }
  if (tid == 0) L[g] = red[0];
}

#if __has_builtin(__builtin_amdgcn_global_load_lds)
#define GLD_LDS(gsrc, ldst) \
  __builtin_amdgcn_global_load_lds((const GAS void*)(gsrc), \
                                   (__attribute__((address_space(3))) void*)(ldst), 16, 0, 0)
#define HAVE_GLD_LDS 1
#else
#define HAVE_GLD_LDS 0
#endif

// ---------------- xp[row][768] = A[row][0..255] @ Wt^T + b0   (bf16 MFMA, 128x128 tiles, BK=32)
// mode 0: A row r gathered from states (f32 -> bf16) via nodeof ; mode 1: A = dense bf16 (y)
__global__ __launch_bounds__(256) void gemm_kernel(
    const float* __restrict__ statesA, const ushortT* __restrict__ Adense,
    const ushortT* __restrict__ Wt, const float* __restrict__ b0,
    const int* __restrict__ nodeof, const int* __restrict__ L,
    ushortT* __restrict__ xp, int layer, int mode)
{
  int mblk = blockIdx.x, nblk = blockIdx.y;
  int g = mblk >> 4;
  int sBase = (mblk & 15) << 7;
  int Lg = L[g];
  if (sBase >= Lg) return;   // whole row-block is padding

  __shared__ __align__(16) ushortT As[128 * 32];
  __shared__ __align__(16) ushortT Bs[128 * 32];

  int tid = threadIdx.x;
  int lane = tid & 63, wid = tid >> 6;
  int wr = wid >> 1, wc = wid & 1;
  f32x4 acc[4][4];
  for (int i = 0; i < 4; i++) for (int n = 0; n < 4; n++) acc[i][n] = (f32x4){0.f,0.f,0.f,0.f};

  for (int kb = 0; kb < 8; ++kb) {
    __syncthreads();
    // stage B: Wt tile [128 cols][32 k] (Wt is pre-transposed: row=col, 512B row stride)
    for (int c = 0; c < 2; ++c) {
      int flat = c * 4096 + tid * 16;
      int col = flat >> 6;
      size_t srcB = ((size_t)(layer * XPW + nblk * 128 + col)) * 512 + kb * 64 + (flat & 63);
#if HAVE_GLD_LDS
      GLD_LDS((const char*)Wt + srcB, (char*)Bs + c * 4096 + wid * 1024);
#else
      *(uint4*)((char*)Bs + flat) = *(const uint4*)((const char*)Wt + srcB);
#endif
    }
    // stage A
    if (mode) {
      for (int c = 0; c < 2; ++c) {
        int flat = c * 4096 + tid * 16;
        int row = flat >> 6;
        size_t srcA = ((size_t)(mblk * 128 + row)) * 512 + kb * 64 + (flat & 63);
#if HAVE_GLD_LDS
        GLD_LDS((const char*)Adense + srcA, (char*)As + c * 4096 + wid * 1024);
#else
        *(uint4*)((char*)As + flat) = *(const uint4*)((const char*)Adense + srcA);
#endif
      }
    } else {
      for (int c = 0; c < 2; ++c) {
        int flat = c * 4096 + tid * 16;
        int row = flat >> 6;
        int s = sBase + row;
        if (s < Lg) {
          int nt = nodeof[g * NPER + s];
          const float* sp = statesA + (size_t)nt * D_DIM + kb * 32 + ((flat & 63) >> 1);
          float4 u0 = *(const float4*)sp;
          float4 u1 = *(const float4*)(sp + 4);
          union { ushortT us[8]; uint4 v; } pk;
          pk.us[0] = f2bf(u0.x); pk.us[1] = f2bf(u0.y); pk.us[2] = f2bf(u0.z); pk.us[3] = f2bf(u0.w);
          pk.us[4] = f2bf(u1.x); pk.us[5] = f2bf(u1.y); pk.us[6] = f2bf(u1.z); pk.us[7] = f2bf(u1.w);
          *(uint4*)((char*)As + flat) = pk.v;
        }
      }
    }
    __syncthreads();

    bf16x8 af[4], bfr[4];
    for (int i = 0; i < 4; i++) {
      int off = (wr * 64 + i * 16 + (lane & 15)) * 32 + (lane >> 4) * 8;
      af[i] = *(const bf16x8*)&As[off];
    }
    for (int n = 0; n < 4; n++) {
      int off = (wc * 64 + n * 16 + (lane & 15)) * 32 + (lane >> 4) * 8;
      bfr[n] = *(const bf16x8*)&Bs[off];
    }
    for (int i = 0; i < 4; i++)
      for (int n = 0; n < 4; n++)
        acc[i][n] = __builtin_amdgcn_mfma_f32_16x16x32_bf16(af[i], bfr[n], acc[i][n], 0, 0, 0);
  }

  // epilogue: + bias, store bf16.  C/D layout: col = lane&15, row = (lane>>4)*4 + v
  for (int n = 0; n < 4; n++) {
    int gcol = nblk * 128 + wc * 64 + n * 16 + (lane & 15);
    float bb = b0[layer * XPW + gcol];
    for (int i = 0; i < 4; i++) {
      int rowBase = mblk * 128 + wr * 64 + i * 16 + (lane >> 4) * 4;
      for (int v = 0; v < 4; v++)
        xp[(size_t)(rowBase + v) * XPW + gcol] = f2bf(acc[i][n][v] + bb);
    }
  }
}

// ---------------- recurrence (MFMA-batched): 1 WG (8 waves, 512 thr) per (16 graphs, dir).
// Per step: H(16 chains x 128 units, f16, LDS ping-pong) @ R(128x384, f16 frags in VGPRs)
// via mfma_f32_16x16x32_f16. Wave w owns unit-tile w: col-tiles {w, 8+w, 16+w} (z,r,h of
// the SAME units -> same lane in D). Gates per lane for chains c=(lane>>4)*4+v. One raw
// s_barrier per step (lgkmcnt-only drain; xp loads / y stores vmcnt-only, stay in flight).
// R/K/b prescaled by log2e (z,r) / 2log2e (h) -> gates use exp2 directly.
// A-frag:  row c = lane&15, k = (lane>>4)*8+e (mirrors working gemm af).
// D:       col j = ut*16 + (lane&15), row c = (lane>>4)*4 + v (mirrors gemm epilogue).
// H LDS [c][k] f16, byte addr XOR-swizzled with ((c&7)<<4) on both write and read.
__global__ __launch_bounds__(512) void rec_kernel(
    const ushortT* __restrict__ xp,
    const float* __restrict__ Rf, const float* __restrict__ Rb,
    const float* __restrict__ bfw, const float* __restrict__ bbw,
    const int* __restrict__ L, ushortT* __restrict__ y, int layer)
{
  int dir = blockIdx.y;
  int g0 = blockIdx.x * 16;
  int tid = threadIdx.x;
  int wave = tid >> 6, lane = tid & 63;
  int jc = lane & 15;           // A-row (chain) for A-frags AND col-within-tile for D
  int qa = lane >> 4;           // 0..3
  int ut = wave;                // unit-tile 0..7
  int j  = ut * 16 + jc;        // unit index / gate column within 128

  __shared__ __align__(16) ushortT Hb[2][16 * 128];   // f16 bits, swizzled

  int Lmax = 0;
  #pragma unroll 1
  for (int i = 0; i < 16; ++i) { int t = L[g0 + i]; Lmax = t > Lmax ? t : Lmax; }
  if (Lmax == 0) return;
  int Lg4[4];
  #pragma unroll
  for (int v = 0; v < 4; ++v) Lg4[v] = L[g0 + qa * 4 + v];

  const float* Rsrc = (dir ? Rb : Rf) + (size_t)layer * U_DIM * TU;
  const float* b1p  = (dir ? bbw : bfw) + layer * 2 * TU + TU;

  // preload B-frags (R columns, f16, prescaled) + biases
  f16x8 bw[3][4];
  float b1s[3];
  #pragma unroll
  for (int gate = 0; gate < 3; ++gate) {
    float sc = (gate < 2) ? LOG2E_F : 2.0f * LOG2E_F;
    int col = gate * 128 + j;
    b1s[gate] = b1p[col] * sc;
    #pragma unroll
    for (int q = 0; q < 4; ++q) {
      union { f16 h[8]; f16x8 v; } pk;
      #pragma unroll
      for (int e = 0; e < 8; ++e) {
        int k = q * 32 + qa * 8 + e;
        pk.h[e] = (f16)(Rsrc[(size_t)k * TU + col] * sc);
      }
      bw[gate][q] = pk.v;
    }
  }

  // zero both H buffers
  for (int i = tid; i < 16 * 128; i += 512) { Hb[0][i] = 0; Hb[1][i] = 0; }
  float hold[4] = {0.f, 0.f, 0.f, 0.f};
  __syncthreads();

  // rolling pointers (xp per chain-v; y per chain-v)
  const ushortT* xptr[4];
  ushortT* yptr[4];
  #pragma unroll
  for (int v = 0; v < 4; ++v) {
    int c = qa * 4 + v;
    int Lg = Lg4[v];
    int pos0 = dir ? (Lg > 0 ? Lg - 1 : 0) : 0;
    xptr[v] = xp + ((size_t)(g0 + c) * NPER + pos0) * XPW + dir * TU + j;
    yptr[v] = y  + ((size_t)(g0 + c) * NPER + pos0) * D_DIM + dir * U_DIM + j;
  }
  const int xstep = dir ? -XPW : XPW;
  const int ystep = dir ? -D_DIM : D_DIM;

  // prologue xp loads for step 0
  ushortT xu[12];
  #pragma unroll
  for (int v = 0; v < 4; ++v) {
    xu[v*3+0] = gload_u16(xptr[v]);
    xu[v*3+1] = gload_u16(xptr[v] + 128);
    xu[v*3+2] = gload_u16(xptr[v] + 256);
  }

  const int abase = jc * 256 + qa * 16;   // + q*64, then XOR
  const int aswz  = (jc & 7) << 4;
  const int cw    = qa * 4;               // chain base for this lane's D rows
  // write byte offsets per v (constant): ((c*256 + j*2)) ^ ((c&7)<<4)
  int wb4[4];
  #pragma unroll
  for (int v = 0; v < 4; ++v) {
    int c = cw + v;
    wb4[v] = (c * 256 + j * 2) ^ ((c & 7) << 4);
  }

  for (int s = 0; s < Lmax; ++s) {
    char* Hrd = (char*)Hb[s & 1];
    char* Hwr = (char*)Hb[(s & 1) ^ 1];
    // A-frags (all waves read same pattern; rows=chains, k split by qa)
    f16x8 afr[4];
    #pragma unroll
    for (int q = 0; q < 4; ++q)
      afr[q] = *(const f16x8*)(Hrd + ((abase + q * 64) ^ aswz));
    // consume current xp, issue next step's loads
    float xf[12];
    #pragma unroll
    for (int i = 0; i < 12; ++i) xf[i] = bf2f(xu[i]);
    #pragma unroll
    for (int v = 0; v < 4; ++v) {
      xptr[v] += xstep;
      xu[v*3+0] = gload_u16(xptr[v]);
      xu[v*3+1] = gload_u16(xptr[v] + 128);
      xu[v*3+2] = gload_u16(xptr[v] + 256);
    }
    // batched matvec: 12 MFMA
    f32x4 accz = {0.f,0.f,0.f,0.f}, accr = {0.f,0.f,0.f,0.f}, acch = {0.f,0.f,0.f,0.f};
    #pragma unroll
    for (int q = 0; q < 4; ++q) {
      accz = __builtin_amdgcn_mfma_f32_16x16x32_f16(afr[q], bw[0][q], accz, 0, 0, 0);
      accr = __builtin_amdgcn_mfma_f32_16x16x32_f16(afr[q], bw[1][q], accr, 0, 0, 0);
      acch = __builtin_amdgcn_mfma_f32_16x16x32_f16(afr[q], bw[2][q], acch, 0, 0, 0);
    }
    // gates: chains c = qa*4 + v
    #pragma unroll
    for (int v = 0; v < 4; ++v) {
      float hz = accz[v] + b1s[0];
      float hr = accr[v] + b1s[1];
      float hh = acch[v] + b1s[2];
      float z = rcpf(1.0f + exp2f_hw(-(xf[v*3+0] + hz)));
      float r = rcpf(1.0f + exp2f_hw(-(xf[v*3+1] + hr)));
      float a = xf[v*3+2] + r * hh;           // already scaled by 2*log2e
      float e = exp2f_hw(__builtin_fabsf(a));
      float th = 1.0f - 2.0f * rcpf(e + 1.0f);
      float cand = __builtin_copysignf(th, a);
      float hnew = cand + z * (hold[v] - cand);
      bool live = s < Lg4[v];
      float hst = live ? hnew : hold[v];
      hold[v] = hst;
      if (live) gstore_u16(yptr[v], f2bf(hst));
      yptr[v] += ystep;
      f16 hph = (f16)hst;
      *(ushortT*)(Hwr + wb4[v]) = __builtin_bit_cast(ushortT, hph);
    }
    asm volatile("s_waitcnt lgkmcnt(0)" ::: "memory");
    __builtin_amdgcn_sched_barrier(0);
    __builtin_amdgcn_s_barrier();
    __builtin_amdgcn_sched_barrier(0);
  }
}

// ---------------- unpack: leaf -> y (bf16->f32), non-leaf -> states copy
__global__ __launch_bounds__(256) void unpack_kernel(
    const float* __restrict__ states, const int* __restrict__ pos,
    const ushortT* __restrict__ y, float* __restrict__ out)
{
  int node = blockIdx.x * 4 + (threadIdx.x >> 6);
  int lane = threadIdx.x & 63;
  int p = pos[node];
  int g = node >> 11;
  float4 v;
  if (p) {
    const ushortT* yp = y + (size_t)(g * NPER + p - 1) * D_DIM + lane * 4;
    v = make_float4(bf2f(yp[0]), bf2f(yp[1]), bf2f(yp[2]), bf2f(yp[3]));
  } else {
    v = *(const float4*)(states + (size_t)node * D_DIM + lane * 4);
  }
  *(float4*)(out + (size_t)node * D_DIM + lane * 4) = v;
}

extern "C" void kernel_launch(void* const* d_in, const int* in_sizes, int n_in,
                              void* d_out, int out_size, void* d_ws, size_t ws_size,
                              hipStream_t stream) {
  const float* states = (const float*)d_in[0];
  const int*   pos    = (const int*)d_in[1];
  // d_in[2] graph_sizes (uniform 2048), d_in[3] training (0) — unused
  const float* Kf  = (const float*)d_in[4];
  const float* Rf  = (const float*)d_in[5];
  const float* bfw = (const float*)d_in[6];
  const float* Kb  = (const float*)d_in[7];
  const float* Rb  = (const float*)d_in[8];
  const float* bbw = (const float*)d_in[9];

  char* ws = (char*)d_ws;
  // layout: L(256B) | nodeof(512KB) | Wt(768KB) | b0(6KB) | xp(201.3MB) | y(67.1MB)  ~= 270MB
  int*     L      = (int*)(ws + 0);
  int*     nodeof = (int*)(ws + 256);
  ushortT* Wt     = (ushortT*)(ws + 524544);
  float*   b0     = (float*)(ws + 1310976);
  ushortT* xp     = (ushortT*)(ws + 1317120);
  ushortT* y      = (ushortT*)(ws + 202643712);

  prep_kernel<<<1542, 256, 0, stream>>>(Kf, Kb, bfw, bbw, Wt, b0);
  nodeofL_kernel<<<64, 256, 0, stream>>>(pos, nodeof, L);

  dim3 ggrid(1024, 6);
  dim3 rgrid(4, 2);    // 4 WGs of 16 graphs x 2 dirs; 16 chains batched per WG via MFMA

  // layer 0
  gemm_kernel<<<ggrid, 256, 0, stream>>>(states, (const ushortT*)nullptr, Wt, b0, nodeof, L, xp, 0, 0);
  rec_kernel<<<rgrid, 512, 0, stream>>>(xp, Rf, Rb, bfw, bbw, L, y, 0);
  // layer 1
  gemm_kernel<<<ggrid, 256, 0, stream>>>(states, y, Wt, b0, nodeof, L, xp, 1, 1);
  rec_kernel<<<rgrid, 512, 0, stream>>>(xp, Rf, Rb, bfw, bbw, L, y, 1);

  unpack_kernel<<<32768, 256, 0, stream>>>(states, pos, y, (float*)d_out);
}